// Round 6
// baseline (105.787 us; speedup 1.0000x reference)
//
#include <hip/hip_runtime.h>

// B=8, M=12, N=32, D=256, C=1024, O=512, BM=96.
//
// Two kernels:
//   kA (128 blocks): A1[o][n] = (R1[o][n] + 2*C1[o][n] - W1[o][33n]) / 512
//                    precomputed from W1 (h = relu(W1@ef) == relu(A1@S)).
//   kM (96 blocks, one per (b,m)): x -> S, Gram, cov; h = relu(A1^T S);
//                    E = sigmoid(W2@h); masked softmax; out = att @ x.
// ws: A1t [32][512] only (16384 floats).

__device__ __forceinline__ float sum4(float4 v){ return v.x+v.y+v.z+v.w; }
__device__ __forceinline__ float dot4(float4 a, float4 b){
    return a.x*b.x + a.y*b.y + a.z*b.z + a.w*b.w;
}
__device__ __forceinline__ void fma4s(float4& a, float s, float4 v){
    a.x += s*v.x; a.y += s*v.y; a.z += s*v.z; a.w += s*v.w;
}

// ---------------- kA: A1 precompute (verified in R4/R5) ---------------------
__global__ __launch_bounds__(256) void kA(const float* __restrict__ W1,
                                          float* __restrict__ A1t) {
    __shared__ float Rl[4][32];
    __shared__ float Cl[4][32];
    int w = threadIdx.x >> 6, l = threadIdx.x & 63;
    int o = blockIdx.x*4 + w;
    const float4* W14 = (const float4*)(W1 + o*1024);
    float4 v0 = W14[l], v1 = W14[l+64], v2 = W14[l+128], v3 = W14[l+192];
    float r0 = sum4(v0), r1 = sum4(v1), r2 = sum4(v2), r3 = sum4(v3);
    #pragma unroll
    for (int m = 1; m < 8; m <<= 1) {
        r0 += __shfl_xor(r0, m, 8);
        r1 += __shfl_xor(r1, m, 8);
        r2 += __shfl_xor(r2, m, 8);
        r3 += __shfl_xor(r3, m, 8);
    }
    float4 cp;
    cp.x = v0.x+v1.x+v2.x+v3.x; cp.y = v0.y+v1.y+v2.y+v3.y;
    cp.z = v0.z+v1.z+v2.z+v3.z; cp.w = v0.w+v1.w+v2.w+v3.w;
    #pragma unroll
    for (int m = 8; m < 64; m <<= 1) {
        cp.x += __shfl_xor(cp.x, m);
        cp.y += __shfl_xor(cp.y, m);
        cp.z += __shfl_xor(cp.z, m);
        cp.w += __shfl_xor(cp.w, m);
    }
    if ((l & 7) == 0) {
        int nb = l >> 3;
        Rl[w][nb]    = r0; Rl[w][nb+8]  = r1;
        Rl[w][nb+16] = r2; Rl[w][nb+24] = r3;
    }
    if (l < 8) *((float4*)&Cl[w][l*4]) = cp;
    __syncthreads();
    if (l < 32) {
        float a = (Rl[w][l] + 2.f*Cl[w][l] - W1[o*1024 + 33*l]) * (1.f/512.f);
        A1t[l*512 + o] = a;
    }
}

// ---------------- kM: everything per (b,m) ----------------------------------
// LDS: xs4 33280 + Gp 18944 + S_l 128 + hl 2080 + el 4096 + att_l 4608
//    = 63136 B (< 64 KB/WG cap).
__global__ __launch_bounds__(256) void kM(const float* __restrict__ x,
                                          const float* __restrict__ A1t,
                                          const float* __restrict__ W2,
                                          float* __restrict__ out) {
    int bm = blockIdx.x;
    int t  = threadIdx.x;
    __shared__ float4 xs4[32][65];                 // full 32x256 x tile
    __shared__ float Gp[4][32][37];                // Gram partials (4 q-slices)
    __shared__ alignas(16) float S_l[32];
    __shared__ alignas(16) float hl[520];          // h vector (512 + pad)
    __shared__ alignas(16) float el[1024];         // E vector
    __shared__ alignas(16) float att_l[32][36];    // cov, then probs

    // phase 1: stage x
    const float4* x4 = (const float4*)x;
    #pragma unroll
    for (int i = 0; i < 8; ++i) {
        int idx = t + 256*i;
        xs4[idx >> 6][idx & 63] = x4[bm*2048 + idx];
    }
    __syncthreads();

    // phase 2a: row sums (32 rows x 8 lanes)
    {
        int n = t >> 3, dq = t & 7;
        float s = 0.f;
        #pragma unroll
        for (int j = 0; j < 8; ++j) s += sum4(xs4[n][dq + 8*j]);
        s += __shfl_xor(s, 1, 8);
        s += __shfl_xor(s, 2, 8);
        s += __shfl_xor(s, 4, 8);
        if (dq == 0) S_l[n] = s;
    }
    // phase 2b: Gram partials — wave w owns q-slice w (q uniform per wave ->
    // conflict-free xs4 row broadcasts). 64 lanes: rt=l>>3, ct=l&7; 4x4 tile
    // rows {rt+8i} x cols {ct+8j}.
    {
        int w = t >> 6, l = t & 63, rt = l >> 3, ct = l & 7;
        float g[4][4];
        #pragma unroll
        for (int i = 0; i < 4; ++i)
            #pragma unroll
            for (int j = 0; j < 4; ++j) g[i][j] = 0.f;
        #pragma unroll 4
        for (int qq = 0; qq < 16; ++qq) {
            int q = w*16 + qq;
            float4 a0 = xs4[rt][q],    a1 = xs4[rt+8][q];
            float4 a2 = xs4[rt+16][q], a3 = xs4[rt+24][q];
            #pragma unroll
            for (int j = 0; j < 4; ++j) {
                float4 b = xs4[ct + 8*j][q];
                g[0][j] += dot4(a0, b); g[1][j] += dot4(a1, b);
                g[2][j] += dot4(a2, b); g[3][j] += dot4(a3, b);
            }
        }
        #pragma unroll
        for (int i = 0; i < 4; ++i)
            #pragma unroll
            for (int j = 0; j < 4; ++j)
                Gp[w][rt + 8*i][ct + 8*j] = g[i][j];
    }
    __syncthreads();

    // phase 3a: cov -> att_l (thread t owns f4 entry: row t>>3, cols 4*(t&7))
    {
        int n = t >> 3, k0 = (t & 7)*4;
        float sn = S_l[n] * (1.f/256.f);
        float4 cv;
        #pragma unroll
        for (int c = 0; c < 4; ++c) {
            float g = Gp[0][n][k0+c] + Gp[1][n][k0+c]
                    + Gp[2][n][k0+c] + Gp[3][n][k0+c];
            float v = g - sn * S_l[k0+c];
            if (c == 0) cv.x = v; else if (c == 1) cv.y = v;
            else if (c == 2) cv.z = v; else cv.w = v;
        }
        *((float4*)&att_l[n][k0]) = cv;
    }
    // phase 3b: h = relu(A1^T S) — waves 2,3 (128 threads, 1 f4 each)
    if (t >= 128) {
        int o4 = t - 128;
        const float4* A4 = (const float4*)A1t;
        float4 hacc = {0.f,0.f,0.f,0.f};
        #pragma unroll 8
        for (int n = 0; n < 32; ++n)
            fma4s(hacc, S_l[n], A4[n*128 + o4]);
        hacc.x = fmaxf(hacc.x, 0.f); hacc.y = fmaxf(hacc.y, 0.f);
        hacc.z = fmaxf(hacc.z, 0.f); hacc.w = fmaxf(hacc.w, 0.f);
        *((float4*)&hl[o4*4]) = hacc;
    }
    __syncthreads();

    // phase 4: E = sigmoid(W2 @ h). 16 groups (cg) x 16 lanes (olane);
    // each group does its 64 c's, staggered by cg to spread el-write banks.
    {
        int olane = t & 15, cg = t >> 4;
        const float4* W24 = (const float4*)W2;
        for (int ci = 0; ci < 64; ++ci) {
            int c = cg*64 + ((ci + cg) & 63);
            float acc = 0.f;
            #pragma unroll
            for (int oo = 0; oo < 8; ++oo) {
                float4 w = W24[c*128 + oo*16 + olane];
                float4 h = *((const float4*)&hl[(oo*16 + olane)*4]);
                acc += dot4(w, h);
            }
            acc += __shfl_xor(acc, 1, 16);
            acc += __shfl_xor(acc, 2, 16);
            acc += __shfl_xor(acc, 4, 16);
            acc += __shfl_xor(acc, 8, 16);
            if (olane == 0)
                el[c] = 1.f / (1.f + __expf(-acc));
        }
    }
    __syncthreads();

    // phase 5: masked softmax (thread t owns f4 entry t; width-8 shfl)
    {
        int r = t >> 3, q = t & 7;
        float4 cv = *((const float4*)&att_l[r][q*4]);
        float4 e  = ((const float4*)el)[t];
        float4 lg;
        lg.x = cv.x > 0.f ? e.x : -1e12f;
        lg.y = cv.y > 0.f ? e.y : -1e12f;
        lg.z = cv.z > 0.f ? e.z : -1e12f;
        lg.w = cv.w > 0.f ? e.w : -1e12f;
        float m = fmaxf(fmaxf(lg.x, lg.y), fmaxf(lg.z, lg.w));
        m = fmaxf(m, __shfl_xor(m, 1, 8));
        m = fmaxf(m, __shfl_xor(m, 2, 8));
        m = fmaxf(m, __shfl_xor(m, 4, 8));
        float4 p;
        p.x = __expf(lg.x - m); p.y = __expf(lg.y - m);
        p.z = __expf(lg.z - m); p.w = __expf(lg.w - m);
        float s = p.x + p.y + p.z + p.w;
        s += __shfl_xor(s, 1, 8);
        s += __shfl_xor(s, 2, 8);
        s += __shfl_xor(s, 4, 8);
        float inv = 1.f / s;
        p.x *= inv; p.y *= inv; p.z *= inv; p.w *= inv;
        *((float4*)&att_l[r][q*4]) = p;
    }
    __syncthreads();

    // phase 6: out = att @ x (full D). tx = f4 col, wy = row-group.
    {
        int tx = t & 63, wy = t >> 6;
        float4* out4 = (float4*)out;
        #pragma unroll
        for (int g = 0; g < 2; ++g) {
            int r0 = wy*8 + g*4;
            float4 acc0={0,0,0,0}, acc1={0,0,0,0}, acc2={0,0,0,0}, acc3={0,0,0,0};
            #pragma unroll
            for (int kq = 0; kq < 8; ++kq) {
                float4 xa = xs4[kq*4+0][tx];
                float4 xb = xs4[kq*4+1][tx];
                float4 xc = xs4[kq*4+2][tx];
                float4 xd = xs4[kq*4+3][tx];
                float4 w0 = *((const float4*)&att_l[r0+0][kq*4]);
                float4 w1 = *((const float4*)&att_l[r0+1][kq*4]);
                float4 w2 = *((const float4*)&att_l[r0+2][kq*4]);
                float4 w3 = *((const float4*)&att_l[r0+3][kq*4]);
                fma4s(acc0,w0.x,xa); fma4s(acc0,w0.y,xb); fma4s(acc0,w0.z,xc); fma4s(acc0,w0.w,xd);
                fma4s(acc1,w1.x,xa); fma4s(acc1,w1.y,xb); fma4s(acc1,w1.z,xc); fma4s(acc1,w1.w,xd);
                fma4s(acc2,w2.x,xa); fma4s(acc2,w2.y,xb); fma4s(acc2,w2.z,xc); fma4s(acc2,w2.w,xd);
                fma4s(acc3,w3.x,xa); fma4s(acc3,w3.y,xb); fma4s(acc3,w3.z,xc); fma4s(acc3,w3.w,xd);
            }
            out4[bm*2048 + (r0+0)*64 + tx] = acc0;
            out4[bm*2048 + (r0+1)*64 + tx] = acc1;
            out4[bm*2048 + (r0+2)*64 + tx] = acc2;
            out4[bm*2048 + (r0+3)*64 + tx] = acc3;
        }
    }
}

extern "C" void kernel_launch(void* const* d_in, const int* in_sizes, int n_in,
                              void* d_out, int out_size, void* d_ws, size_t ws_size,
                              hipStream_t stream) {
    const float* x  = (const float*)d_in[0];
    const float* W1 = (const float*)d_in[1];
    const float* W2 = (const float*)d_in[2];
    float* out = (float*)d_out;
    float* A1t = (float*)d_ws;   // 16384 floats

    kA<<<128, 256, 0, stream>>>(W1, A1t);
    kM<<<96, 256, 0, stream>>>(x, A1t, W2, out);
}

// Round 7
// 83.988 us; speedup vs baseline: 1.2595x; 1.2595x over previous
//
#include <hip/hip_runtime.h>

// B=8, M=12, N=32, D=256, C=1024, O=512, BM=96.
//
// kA (128): A1[o][n] = (R1[o][n] + 2*C1[o][n] - W1[o][33n])/512 from W1.
// kC (96):  per (b,m): x -> S, Gram, cov -> ws; h = relu(A1^T S) -> ws.
// kE (16x12): E = sigmoid(W2 @ h) with W2 read 12x (L3-resident).
// kO (192): masked softmax + att @ x.
//
// ws (floats): A1t [32][512] off 0 | covg [96][1024] off 16384
//              | Ht [96][512] off 114688

__device__ __forceinline__ float sum4(float4 v){ return v.x+v.y+v.z+v.w; }
__device__ __forceinline__ float dot4(float4 a, float4 b){
    return a.x*b.x + a.y*b.y + a.z*b.z + a.w*b.w;
}
__device__ __forceinline__ void fma4s(float4& a, float s, float4 v){
    a.x += s*v.x; a.y += s*v.y; a.z += s*v.z; a.w += s*v.w;
}

// ---------------- kA: A1 precompute (verified R4-R6) ------------------------
__global__ __launch_bounds__(256) void kA(const float* __restrict__ W1,
                                          float* __restrict__ A1t) {
    __shared__ float Rl[4][32];
    __shared__ float Cl[4][32];
    int w = threadIdx.x >> 6, l = threadIdx.x & 63;
    int o = blockIdx.x*4 + w;
    const float4* W14 = (const float4*)(W1 + o*1024);
    float4 v0 = W14[l], v1 = W14[l+64], v2 = W14[l+128], v3 = W14[l+192];
    float r0 = sum4(v0), r1 = sum4(v1), r2 = sum4(v2), r3 = sum4(v3);
    #pragma unroll
    for (int m = 1; m < 8; m <<= 1) {
        r0 += __shfl_xor(r0, m, 8);
        r1 += __shfl_xor(r1, m, 8);
        r2 += __shfl_xor(r2, m, 8);
        r3 += __shfl_xor(r3, m, 8);
    }
    float4 cp;
    cp.x = v0.x+v1.x+v2.x+v3.x; cp.y = v0.y+v1.y+v2.y+v3.y;
    cp.z = v0.z+v1.z+v2.z+v3.z; cp.w = v0.w+v1.w+v2.w+v3.w;
    #pragma unroll
    for (int m = 8; m < 64; m <<= 1) {
        cp.x += __shfl_xor(cp.x, m);
        cp.y += __shfl_xor(cp.y, m);
        cp.z += __shfl_xor(cp.z, m);
        cp.w += __shfl_xor(cp.w, m);
    }
    if ((l & 7) == 0) {
        int nb = l >> 3;
        Rl[w][nb]    = r0; Rl[w][nb+8]  = r1;
        Rl[w][nb+16] = r2; Rl[w][nb+24] = r3;
    }
    if (l < 8) *((float4*)&Cl[w][l*4]) = cp;
    __syncthreads();
    if (l < 32) {
        float a = (Rl[w][l] + 2.f*Cl[w][l] - W1[o*1024 + 33*l]) * (1.f/512.f);
        A1t[l*512 + o] = a;
    }
}

// ---------------- kC: per-(b,m) S + Gram + cov + h --------------------------
// LDS: xs4 33280 + Gp 18944 + S_l 128 = 52352 B -> 3 blocks/CU.
__global__ __launch_bounds__(256) void kC(const float* __restrict__ x,
                                          const float* __restrict__ A1t,
                                          float* __restrict__ covg,
                                          float* __restrict__ Ht) {
    int bm = blockIdx.x;
    int t  = threadIdx.x;
    __shared__ float4 xs4[32][65];
    __shared__ float Gp[4][32][37];
    __shared__ alignas(16) float S_l[32];

    const float4* x4 = (const float4*)x;
    #pragma unroll
    for (int i = 0; i < 8; ++i) {
        int idx = t + 256*i;
        xs4[idx >> 6][idx & 63] = x4[bm*2048 + idx];
    }
    __syncthreads();
    // row sums
    {
        int n = t >> 3, dq = t & 7;
        float s = 0.f;
        #pragma unroll
        for (int j = 0; j < 8; ++j) s += sum4(xs4[n][dq + 8*j]);
        s += __shfl_xor(s, 1, 8);
        s += __shfl_xor(s, 2, 8);
        s += __shfl_xor(s, 4, 8);
        if (dq == 0) S_l[n] = s;
    }
    // Gram partials: wave w owns q-slice w (wave-uniform q -> broadcasts)
    {
        int w = t >> 6, l = t & 63, rt = l >> 3, ct = l & 7;
        float g[4][4];
        #pragma unroll
        for (int i = 0; i < 4; ++i)
            #pragma unroll
            for (int j = 0; j < 4; ++j) g[i][j] = 0.f;
        #pragma unroll 4
        for (int qq = 0; qq < 16; ++qq) {
            int q = w*16 + qq;
            float4 a0 = xs4[rt][q],    a1 = xs4[rt+8][q];
            float4 a2 = xs4[rt+16][q], a3 = xs4[rt+24][q];
            #pragma unroll
            for (int j = 0; j < 4; ++j) {
                float4 b = xs4[ct + 8*j][q];
                g[0][j] += dot4(a0, b); g[1][j] += dot4(a1, b);
                g[2][j] += dot4(a2, b); g[3][j] += dot4(a3, b);
            }
        }
        #pragma unroll
        for (int i = 0; i < 4; ++i)
            #pragma unroll
            for (int j = 0; j < 4; ++j)
                Gp[w][rt + 8*i][ct + 8*j] = g[i][j];
    }
    __syncthreads();
    // cov -> global (all 256 threads, 1 f4 each)
    {
        int n = t >> 3, k0 = (t & 7)*4;
        float sn = S_l[n] * (1.f/256.f);
        float4 cv;
        #pragma unroll
        for (int c = 0; c < 4; ++c) {
            float g = Gp[0][n][k0+c] + Gp[1][n][k0+c]
                    + Gp[2][n][k0+c] + Gp[3][n][k0+c];
            float v = g - sn * S_l[k0+c];
            if (c == 0) cv.x = v; else if (c == 1) cv.y = v;
            else if (c == 2) cv.z = v; else cv.w = v;
        }
        ((float4*)covg)[bm*256 + t] = cv;
    }
    // h = relu(A1^T S) -> global (threads 0..127, 1 f4 each, coalesced)
    if (t < 128) {
        const float4* A4 = (const float4*)A1t;
        float4 hacc = {0.f,0.f,0.f,0.f};
        #pragma unroll 8
        for (int n = 0; n < 32; ++n)
            fma4s(hacc, S_l[n], A4[n*128 + t]);
        hacc.x = fmaxf(hacc.x, 0.f); hacc.y = fmaxf(hacc.y, 0.f);
        hacc.z = fmaxf(hacc.z, 0.f); hacc.w = fmaxf(hacc.w, 0.f);
        ((float4*)Ht)[bm*128 + t] = hacc;
    }
}

// ---------------- kE: E = sigmoid(W2 @ h) -----------------------------------
// grid (16 cT x 12 bmG); block 256 = 16 olane x 16 cg (R5 proven, no spill).
__global__ __launch_bounds__(256) void kE(const float* __restrict__ W2,
                                          const float* __restrict__ Ht,
                                          float* __restrict__ Et) {
    __shared__ float hl[8][516];    // pad 4
    int t = threadIdx.x;
    int cT = blockIdx.x, bmG = blockIdx.y;
    const float4* Ht4 = (const float4*)Ht;
    #pragma unroll
    for (int i = 0; i < 4; ++i) {
        int idx = t + 256*i;              // 1024 = 8 bm x 128 f4
        int bl = idx >> 7, o4 = idx & 127;
        *((float4*)&hl[bl][o4*4]) = Ht4[(bmG*8 + bl)*128 + o4];
    }
    __syncthreads();
    {
        int olane = t & 15, cg = t >> 4;
        const float4* W24 = (const float4*)W2;
        #pragma unroll
        for (int ci = 0; ci < 4; ++ci) {
            int c = cT*64 + cg*4 + ci;
            float acc[8] = {0.f,0.f,0.f,0.f,0.f,0.f,0.f,0.f};
            #pragma unroll
            for (int oo = 0; oo < 8; ++oo) {
                float4 w = W24[c*128 + oo*16 + olane];
                #pragma unroll
                for (int bl = 0; bl < 8; ++bl)
                    acc[bl] += dot4(w, *((const float4*)&hl[bl][(oo*16+olane)*4]));
            }
            #pragma unroll
            for (int bl = 0; bl < 8; ++bl) {
                float a = acc[bl];
                a += __shfl_xor(a, 1, 16);
                a += __shfl_xor(a, 2, 16);
                a += __shfl_xor(a, 4, 16);
                a += __shfl_xor(a, 8, 16);
                if (olane == 0)
                    Et[(bmG*8 + bl)*1024 + c] = 1.f / (1.f + __expf(-a));
            }
        }
    }
}

// ---------------- kO: mask + softmax + att@x (per bm x d-half) --------------
__global__ __launch_bounds__(256) void kO(const float* __restrict__ x,
                                          const float* __restrict__ covg,
                                          const float* __restrict__ Et,
                                          float* __restrict__ out) {
    int bm = blockIdx.x >> 1;
    int h  = blockIdx.x & 1;
    int t  = threadIdx.x;
    __shared__ float4 xs4[32][33];
    __shared__ float att_l[32][36];
    const float4* x4 = (const float4*)x;
    #pragma unroll
    for (int i = 0; i < 4; ++i) {
        int idx = t + 256*i;
        int n = idx >> 5, dq = idx & 31;
        xs4[n][dq] = x4[bm*2048 + n*64 + h*32 + dq];
    }
    {
        float4 cv = ((const float4*)covg)[bm*256 + t];
        float4 e  = ((const float4*)Et)[bm*256 + t];
        float4 lg;
        lg.x = cv.x > 0.f ? e.x : -1e12f;
        lg.y = cv.y > 0.f ? e.y : -1e12f;
        lg.z = cv.z > 0.f ? e.z : -1e12f;
        lg.w = cv.w > 0.f ? e.w : -1e12f;
        float m = fmaxf(fmaxf(lg.x, lg.y), fmaxf(lg.z, lg.w));
        m = fmaxf(m, __shfl_xor(m, 1, 8));
        m = fmaxf(m, __shfl_xor(m, 2, 8));
        m = fmaxf(m, __shfl_xor(m, 4, 8));
        float4 p;
        p.x = __expf(lg.x - m); p.y = __expf(lg.y - m);
        p.z = __expf(lg.z - m); p.w = __expf(lg.w - m);
        float s = p.x + p.y + p.z + p.w;
        s += __shfl_xor(s, 1, 8);
        s += __shfl_xor(s, 2, 8);
        s += __shfl_xor(s, 4, 8);
        float inv = 1.f / s;
        p.x *= inv; p.y *= inv; p.z *= inv; p.w *= inv;
        *((float4*)&att_l[t >> 3][(t & 7)*4]) = p;
    }
    __syncthreads();
    {
        int txl = t & 31, wy = t >> 5;
        int r0 = wy*4;
        float4 acc0={0,0,0,0}, acc1={0,0,0,0}, acc2={0,0,0,0}, acc3={0,0,0,0};
        #pragma unroll
        for (int kq = 0; kq < 8; ++kq) {
            float4 xa = xs4[kq*4+0][txl];
            float4 xb = xs4[kq*4+1][txl];
            float4 xc = xs4[kq*4+2][txl];
            float4 xd = xs4[kq*4+3][txl];
            float4 w0 = *((const float4*)&att_l[r0+0][kq*4]);
            float4 w1 = *((const float4*)&att_l[r0+1][kq*4]);
            float4 w2 = *((const float4*)&att_l[r0+2][kq*4]);
            float4 w3 = *((const float4*)&att_l[r0+3][kq*4]);
            fma4s(acc0,w0.x,xa); fma4s(acc0,w0.y,xb); fma4s(acc0,w0.z,xc); fma4s(acc0,w0.w,xd);
            fma4s(acc1,w1.x,xa); fma4s(acc1,w1.y,xb); fma4s(acc1,w1.z,xc); fma4s(acc1,w1.w,xd);
            fma4s(acc2,w2.x,xa); fma4s(acc2,w2.y,xb); fma4s(acc2,w2.z,xc); fma4s(acc2,w2.w,xd);
            fma4s(acc3,w3.x,xa); fma4s(acc3,w3.y,xb); fma4s(acc3,w3.z,xc); fma4s(acc3,w3.w,xd);
        }
        float4* out4 = (float4*)out;
        out4[bm*2048 + (r0+0)*64 + h*32 + txl] = acc0;
        out4[bm*2048 + (r0+1)*64 + h*32 + txl] = acc1;
        out4[bm*2048 + (r0+2)*64 + h*32 + txl] = acc2;
        out4[bm*2048 + (r0+3)*64 + h*32 + txl] = acc3;
    }
}

extern "C" void kernel_launch(void* const* d_in, const int* in_sizes, int n_in,
                              void* d_out, int out_size, void* d_ws, size_t ws_size,
                              hipStream_t stream) {
    const float* x  = (const float*)d_in[0];
    const float* W1 = (const float*)d_in[1];
    const float* W2 = (const float*)d_in[2];
    float* out = (float*)d_out;
    float* ws  = (float*)d_ws;

    float* A1t  = ws;               // 16384 floats
    float* covg = ws + 16384;       // 98304
    float* Ht   = ws + 114688;      // 49152
    float* Et   = ws + 163840;      // 98304

    kA<<<128, 256, 0, stream>>>(W1, A1t);
    kC<<<96, 256, 0, stream>>>(x, A1t, covg, Ht);
    kE<<<dim3(16, 12), 256, 0, stream>>>(W2, Ht, Et);
    kO<<<192, 256, 0, stream>>>(x, covg, Et, out);
}